// Round 18
// baseline (270.171 us; speedup 1.0000x reference)
//
#include <hip/hip_runtime.h>
#include <hip/hip_bf16.h>
#include <stdint.h>

#define TEMPERATURE 0.07f
#define SC 20.6099312f   // log2(e)/T  (SC*ln2 == 1/T; cancellation used in rowfin)

constexpr int NQ = 256;
constexpr int KQ = 8192;
constexpr int D  = 128;
constexpr int N  = NQ + 2 * KQ;   // 16640
constexpr int CS = 26;            // column splits (130 tiles / 26 = exactly 5 per block)
constexpr int CS2 = CS * 2;       // part slots
constexpr int BN = 128;           // columns per tile
constexpr int RBM = N / 128;      // 130 row blocks for k_main
constexpr int PB = 520;           // k_prep blocks (32 rows each)

typedef float f32x16 __attribute__((ext_vector_type(16)));
typedef int   i32x4  __attribute__((ext_vector_type(4)));
typedef int   i32x8  __attribute__((ext_vector_type(8)));

// ---- workspace layout (bytes) ----
constexpr size_t OFF_F32  = 0;                                    // float feat [NQ][D] (q rows only)
constexpr size_t OFF_8    = OFF_F32  + (size_t)NQ * D * 4;        // fp8 feat (A side) [N][128]
constexpr size_t OFF_8S   = OFF_8    + (size_t)N * D;             // fp8 feat * SC (B side) [N][128]
constexpr size_t OFF_PART = OFF_8S   + (size_t)N * D;             // partials [CS2][N]
constexpr size_t OFF_ATOM = OFF_PART + (size_t)CS2 * N * 4;       // atomics (below)
// atom layout (8B units): iS[0..255], rbdone[256..255+130], lacc[390], done2[391]
constexpr int AT_RBD = 256;
constexpr int AT_LACC = 390;
constexpr int AT_DONE2 = 391;
constexpr size_t ATOM_BYTES = 392 * 8;

#define MFMA8(a, b, c) __builtin_amdgcn_mfma_scale_f32_32x32x64_f8f6f4( \
    (a), (b), (c), 0, 0, 0, 0x7f7f7f7f, 0, 0x7f7f7f7f)

// ---------------------------------------------------------------------------
// K1: normalize features; emit f32 (q rows only) + two natural-row-major fp8
// copies (unscaled A side, SC-prescaled B side). Per-label per-dim partials
// accumulate into int64 fixed-point (scale 2^32) via atomics (deterministic).
// ---------------------------------------------------------------------------
__global__ __launch_bounds__(256) void k_prep(const float* __restrict__ q,
                                              const float* __restrict__ ba,
                                              const float* __restrict__ nb,
                                              const long long* __restrict__ tgt,
                                              float* __restrict__ ff,
                                              unsigned char* __restrict__ fb8,
                                              unsigned char* __restrict__ fb8s,
                                              unsigned long long* __restrict__ iS) {
    __shared__ float red[4][2][128];
    int wid = threadIdx.x >> 6, lane = threadIdx.x & 63;
    int rbase = blockIdx.x * 32 + wid * 8;
    float s0x = 0.f, s0y = 0.f, s1x = 0.f, s1y = 0.f;
    #pragma unroll
    for (int i = 0; i < 8; ++i) {
        int r = rbase + i;
        const float* src = (r < NQ) ? (q + (size_t)r * D)
                         : (r < NQ + KQ) ? (ba + (size_t)(r - NQ) * D)
                         : (nb + (size_t)(r - NQ - KQ) * D);
        float2 v = *(const float2*)(src + lane * 2);
        float a = v.x, b = v.y;
        int lab;
        if (r < NQ) {
            float ss = a * a + b * b;
            #pragma unroll
            for (int m = 1; m < 64; m <<= 1) ss += __shfl_xor(ss, m);
            float scale = 1.0f / fmaxf(sqrtf(ss), 1e-12f);
            a *= scale; b *= scale;
            lab = (int)tgt[r];
            *(float2*)(ff + (size_t)r * D + lane * 2) = make_float2(a, b);
        } else {
            lab = (r < NQ + KQ) ? 1 : 0;
        }
        int w8  = __builtin_amdgcn_cvt_pk_fp8_f32(a, b, 0, false);
        int w8s = __builtin_amdgcn_cvt_pk_fp8_f32(a * SC, b * SC, 0, false);
        *(unsigned short*)(fb8  + (size_t)r * D + lane * 2) = (unsigned short)w8;
        *(unsigned short*)(fb8s + (size_t)r * D + lane * 2) = (unsigned short)w8s;
        if (lab) { s1x += a; s1y += b; } else { s0x += a; s0y += b; }
    }
    red[wid][0][lane * 2]     = s0x;
    red[wid][0][lane * 2 + 1] = s0y;
    red[wid][1][lane * 2]     = s1x;
    red[wid][1][lane * 2 + 1] = s1y;
    __syncthreads();
    int lab2 = threadIdx.x >> 7, d = threadIdx.x & 127;
    float s = red[0][lab2][d] + red[1][lab2][d] + red[2][lab2][d] + red[3][lab2][d];
    long long fx = __double2ll_rn((double)s * 4294967296.0);   // 2^32 fixed-point
    atomicAdd(&iS[lab2 * 128 + d], (unsigned long long)fx);
}

// ---------------------------------------------------------------------------
// K3: main fused MX-fp8 GEMM + exp row-sum (R12/R15 body, verbatim) + FUSED
// rowfin tail: the 26th block to finish a row-group rb performs the per-row
// finalize for rb's 128 rows, reusing the (now free) LDS. Loss sum via int64
// atomics; the 130th rb-finisher writes out[0]. All fixed-order/int -> det.
// ---------------------------------------------------------------------------
__global__ __launch_bounds__(256, 4) void k_main(const unsigned char* __restrict__ fb8,
                                                 const unsigned char* __restrict__ fb8s,
                                                 const float* __restrict__ ff,
                                                 const float* __restrict__ ba,
                                                 const float* __restrict__ nb,
                                                 const long long* __restrict__ tgt,
                                                 float* __restrict__ part,
                                                 unsigned long long* __restrict__ atom,
                                                 float* __restrict__ out) {
    __shared__ __align__(16) unsigned char lds[2][BN * 128];   // 2 x 16KB
    __shared__ unsigned long long tick;
    const int bid = blockIdx.x;
    const int rb = bid / CS, cs = bid % CS;
    const int tid = threadIdx.x;
    const int lane = tid & 63;
    const int wid  = tid >> 6;                 // 0..3
    const int wr = wid >> 1, wc = wid & 1;     // 2x2 wave grid
    const int l31 = lane & 31, lhi = lane >> 5;
    const int rw = rb * 128 + wr * 64;         // this wave's 64 rows

    // staging: 4 issues x 16B per thread; dest linear, source inverts swizzle.
    int soff[4];
    #pragma unroll
    for (int i = 0; i < 4; ++i) {
        int flat = i * 256 + tid;
        int line = flat >> 4, p = flat & 15;
        int pl = p ^ (line & 15);
        soff[i] = (2 * line + (pl >> 3)) * 128 + (pl & 7) * 16;
    }

#define STAGE(T, B) { \
    const unsigned char* base_ = fb8 + ((size_t)(cs + (T) * CS)) * (BN * 128); \
    _Pragma("unroll") \
    for (int i_ = 0; i_ < 4; ++i_) \
        __builtin_amdgcn_global_load_lds( \
            (const __attribute__((address_space(1))) unsigned int*)(base_ + soff[i_]), \
            (__attribute__((address_space(3))) unsigned int*)(&lds[B][(i_ * 256 + tid) * 16]), \
            16, 0, 0); }

#define SYNC() { asm volatile("s_waitcnt vmcnt(0)" ::: "memory"); __builtin_amdgcn_s_barrier(); }

    // rf: B operand (scaled side), 2 row-groups x 2 K-steps x 32B, loaded once.
    i32x8 rf[2][2];
    #pragma unroll
    for (int rs = 0; rs < 2; ++rs)
        #pragma unroll
        for (int s = 0; s < 2; ++s)
            rf[rs][s] = *(const i32x8*)(fb8s + (size_t)(rw + rs * 32 + l31) * D + s * 64 + lhi * 32);

    f32x16 z16;
    #pragma unroll
    for (int e = 0; e < 16; ++e) z16[e] = 0.f;

    float2 ps2[2] = {{0.f, 0.f}, {0.f, 0.f}};

    STAGE(0, 0) SYNC()

    #pragma unroll 1
    for (int t = 0; t < 5; ++t) {
        if (t + 1 < 5) STAGE(t + 1, (t & 1) ^ 1)
        const unsigned char* buf = &lds[t & 1][0];

        f32x16 acc[2][2];
        __builtin_amdgcn_s_setprio(1);
        #pragma unroll
        for (int s = 0; s < 2; ++s) {
            #pragma unroll
            for (int cc = 0; cc < 2; ++cc) {
                int crow = wc * 64 + cc * 32 + l31;
                int line = crow >> 1;
                int pb = ((crow & 1) << 3) + s * 4 + lhi * 2;
                const unsigned char* lb = buf + line * 256;
                i32x4 lo = *(const i32x4*)(lb + ((pb    ) ^ (line & 15)) * 16);
                i32x4 hi = *(const i32x4*)(lb + ((pb + 1) ^ (line & 15)) * 16);
                i32x8 a = {lo[0], lo[1], lo[2], lo[3], hi[0], hi[1], hi[2], hi[3]};
                acc[cc][0] = MFMA8(a, rf[0][s], (s == 0) ? z16 : acc[cc][0]);
                acc[cc][1] = MFMA8(a, rf[1][s], (s == 0) ? z16 : acc[cc][1]);
            }
        }
        __builtin_amdgcn_s_setprio(0);

        // epilogue: e = exp2(acc) (raw domain), pairwise accumulation.
        #pragma unroll
        for (int cc = 0; cc < 2; ++cc)
            #pragma unroll
            for (int rs = 0; rs < 2; ++rs) {
                float2 p = {0.f, 0.f};
                #pragma unroll
                for (int g = 0; g < 8; ++g) {
                    p.x += __builtin_amdgcn_exp2f(acc[cc][rs][2 * g]);
                    p.y += __builtin_amdgcn_exp2f(acc[cc][rs][2 * g + 1]);
                }
                ps2[rs].x += p.x; ps2[rs].y += p.y;
            }

        SYNC()
    }

    // lane l and l^32 hold the same output row (complementary column subsets).
    float rsum[2] = {ps2[0].x + ps2[0].y, ps2[1].x + ps2[1].y};
    rsum[0] += __shfl_xor(rsum[0], 32);
    rsum[1] += __shfl_xor(rsum[1], 32);
    if (lane < 32) {
        float* dst = part + (size_t)(cs * 2 + wc) * N + rw + lane;
        dst[0]  = rsum[0];
        dst[32] = rsum[1];
    }

    // ---- fused rowfin: last block of this rb finalizes its 128 rows ------
    __syncthreads();                       // drains part stores (vmcnt) too
    if (tid == 0) {
        __threadfence();                   // release: L2 writeback of part
        tick = atomicAdd(&atom[AT_RBD + rb], 1ull);
    }
    __syncthreads();
    if (tick != (unsigned long long)(CS - 1)) return;
    __threadfence();                       // acquire side

    // LDS reuse (main loop done): sS[256] | pse[2][128] | pdS[2][128] | pdd[2][128] | red[128]
    float* sS  = (float*)&lds[0][0];
    float* pse = sS + 256;
    float* pdS = pse + 256;
    float* pdd = pdS + 256;
    float* red = pdd + 256;
    __shared__ int scnt[2];

    sS[tid] = (float)((double)(long long)atom[tid] * (1.0 / 4294967296.0));
    if (tid < 64) {
        int c = 0;
        #pragma unroll
        for (int i = 0; i < 4; ++i) c += (int)tgt[tid + 64 * i];
        #pragma unroll
        for (int m = 1; m < 64; m <<= 1) c += __shfl_xor(c, m);
        if (tid == 0) { scnt[0] = (NQ - c) + KQ; scnt[1] = c + KQ; }
    }
    __syncthreads();

    {
        int h = tid >> 7, rr = tid & 127;
        int r = rb * 128 + rr;
        float se = 0.f;
        #pragma unroll 2
        for (int c = h * CS; c < h * CS + CS; ++c) se += part[(size_t)c * N + r];
        int lab = (r < NQ) ? (int)tgt[r] : ((r < NQ + KQ) ? 1 : 0);
        const float* fsrc = (r < NQ) ? (ff + (size_t)r * D)
                          : (r < NQ + KQ) ? (ba + (size_t)(r - NQ) * D)
                          : (nb + (size_t)(r - NQ - KQ) * D);
        const float4* frow = (const float4*)(fsrc + h * 64);
        const float4* srow = (const float4*)(sS + lab * 128 + h * 64);
        float dS = 0.f, dd = 0.f;
        #pragma unroll
        for (int i = 0; i < 16; ++i) {
            float4 f = frow[i];
            float4 s = srow[i];
            dS += f.x * s.x + f.y * s.y + f.z * s.z + f.w * s.w;
            int wa  = __builtin_amdgcn_cvt_pk_fp8_f32(f.x, f.y, 0, false);
            int wb  = __builtin_amdgcn_cvt_pk_fp8_f32(f.z, f.w, 0, false);
            int wsa = __builtin_amdgcn_cvt_pk_fp8_f32(f.x * SC, f.y * SC, 0, false);
            int wsb = __builtin_amdgcn_cvt_pk_fp8_f32(f.z * SC, f.w * SC, 0, false);
            dd += __builtin_amdgcn_cvt_f32_fp8(wa, 0) * __builtin_amdgcn_cvt_f32_fp8(wsa, 0)
                + __builtin_amdgcn_cvt_f32_fp8(wa, 1) * __builtin_amdgcn_cvt_f32_fp8(wsa, 1)
                + __builtin_amdgcn_cvt_f32_fp8(wb, 0) * __builtin_amdgcn_cvt_f32_fp8(wsb, 0)
                + __builtin_amdgcn_cvt_f32_fp8(wb, 1) * __builtin_amdgcn_cvt_f32_fp8(wsb, 1);
        }
        pse[h * 128 + rr] = se;
        pdS[h * 128 + rr] = dS;
        pdd[h * 128 + rr] = dd;
    }
    __syncthreads();

    if (tid < 128) {
        int rr = tid;
        int r = rb * 128 + rr;
        float se = pse[rr] + pse[128 + rr];
        float dS = pdS[rr] + pdS[128 + rr];
        float dd = pdd[rr] + pdd[128 + rr];
        se -= __builtin_amdgcn_exp2f(dd);
        float lse = logf(se);
        int lab = (r < NQ) ? (int)tgt[r] : ((r < NQ + KQ) ? 1 : 0);
        float P = (float)(scnt[lab] - 1);
        red[rr] = (dS - 1.0f) / (TEMPERATURE * P) - lse;
    }
    __syncthreads();
    for (int s2 = 64; s2 > 0; s2 >>= 1) {
        if (tid < s2) red[tid] += red[tid + s2];
        __syncthreads();
    }
    if (tid == 0) {
        long long fx = __double2ll_rn((double)red[0] * 16777216.0);   // 2^24 fixed-point
        atomicAdd(&atom[AT_LACC], (unsigned long long)fx);
        __threadfence();
        unsigned long long old = atomicAdd(&atom[AT_DONE2], 1ull);
        if (old == (unsigned long long)(RBM - 1)) {
            __threadfence();
            long long tot = (long long)atomicAdd(&atom[AT_LACC], 0ull);
            out[0] = (float)(-((double)tot * (1.0 / 16777216.0)) / (double)N);
        }
    }
#undef STAGE
#undef SYNC
}

extern "C" void kernel_launch(void* const* d_in, const int* in_sizes, int n_in,
                              void* d_out, int out_size, void* d_ws, size_t ws_size,
                              hipStream_t stream) {
    const float* q       = (const float*)d_in[0];
    const float* ba      = (const float*)d_in[1];
    const float* nb      = (const float*)d_in[2];
    const long long* tgt = (const long long*)d_in[3];
    char* ws = (char*)d_ws;
    float*              ff   = (float*)(ws + OFF_F32);
    unsigned char*      fb8  = (unsigned char*)(ws + OFF_8);
    unsigned char*      fb8s = (unsigned char*)(ws + OFF_8S);
    float*              part = (float*)(ws + OFF_PART);
    unsigned long long* atom = (unsigned long long*)(ws + OFF_ATOM);

    hipMemsetAsync(atom, 0, ATOM_BYTES, stream);   // zero iS + rbdone + lacc + done2
    k_prep<<<PB,       256, 0, stream>>>(q, ba, nb, tgt, ff, fb8, fb8s, atom);
    k_main<<<RBM * CS, 256, 0, stream>>>(fb8, fb8s, ff, ba, nb, tgt, part, atom,
                                         (float*)d_out);
}